// Round 5
// baseline (424.375 us; speedup 1.0000x reference)
//
#include <hip/hip_runtime.h>
#include <math.h>

#if __has_builtin(__builtin_amdgcn_exp2f)
#define EXP2(x) __builtin_amdgcn_exp2f(x)
#else
#define EXP2(x) exp2f(x)
#endif

#define ALPHA_LRELU 0.2f
#define LOG2E 1.4426950408889634f
#define ESHIFT 6.0f
#define BIGM 1024.0f  // bit=0 -> exp2 arg < -1000 -> p = 0

constexpr int Bc = 2, Nn = 2048, Ff = 256, Hh = 8, Oo = 32;
constexpr int NC = Nn / 64;  // j-chunks of 64

typedef _Float16 f16;
typedef f16 f16x8 __attribute__((ext_vector_type(8)));
typedef f16 f16x4 __attribute__((ext_vector_type(4)));
typedef float f32x4 __attribute__((ext_vector_type(4)));
typedef unsigned long long u64;
typedef unsigned short u16;

__global__ __launch_bounds__(256) void zero_kernel(float* __restrict__ p) {
    p[blockIdx.x * 256 + threadIdx.x] = 0.f;
}

// ---------------------------------------------------------------------------
// adj -> bitmask (u64 words; little-endian so u16 sub-words index j cleanly)
// ---------------------------------------------------------------------------
__global__ __launch_bounds__(256) void pack_kernel(
    const int* __restrict__ adj, u64* __restrict__ mask) {
    int idx = blockIdx.x * 256 + threadIdx.x;
    u64 b = __ballot(adj[idx] != 0);
    if ((threadIdx.x & 63) == 0) mask[idx >> 6] = b;
}

// ---------------------------------------------------------------------------
// Weights: WT[y][c][k] f16 (k contiguous), y = l*2+stage.
// ---------------------------------------------------------------------------
__global__ __launch_bounds__(256) void wt_kernel(
    const float* __restrict__ W_heads, const float* __restrict__ W_out,
    f16* __restrict__ WT) {
    int t = threadIdx.x;
    int y = blockIdx.y;
    int l = y >> 1, st = y & 1;
    int c = blockIdx.x * 4 + (t >> 6);
    int k0 = (t & 63) * 4;
    const float* src;
    int stride;
    if (st == 0) {
        src = W_heads + (((size_t)l * Hh + (c >> 5)) * Ff) * Oo + (c & 31);
        stride = Oo;
    } else {
        src = W_out + (size_t)l * Ff * Ff + c;
        stride = Ff;
    }
    f16x4 v;
#pragma unroll
    for (int i = 0; i < 4; ++i) v[i] = (f16)src[(size_t)(k0 + i) * stride];
    *(f16x4*)&WT[((size_t)y * Ff + c) * Ff + k0] = v;
}

// ---------------------------------------------------------------------------
// Barrier-free MFMA GEMM: wave-private 16 rows x 64 cols, K=256.
// A-frags loaded straight from global fp32 (A[m=am][k=aq*8..+8]) and packed
// to f16 in registers -> NO LDS, NO __syncthreads. B-frags from global WT f16
// (L1/L2-hot), prefetched one K-step ahead. Fused epilogue: CT + s1/s2.
// ---------------------------------------------------------------------------
__global__ __launch_bounds__(256) void gemm_wave(
    const float* __restrict__ A, const f16* __restrict__ WT,
    const float* __restrict__ pa, f16* __restrict__ CT,
    float* __restrict__ s1, float* __restrict__ s2,
    int G, int Ofull, int oshift) {
    int t = threadIdx.x;
    int w = t >> 6, lane = t & 63;
    int am = lane & 15, aq = lane >> 4;
    int m0 = blockIdx.x * 64 + w * 16;
    int colb = blockIdx.y * 64;

    const float* aptr = A + (size_t)(m0 + am) * Ff + aq * 8;
    const f16* bp0 = WT + (size_t)(colb + am) * Ff + aq * 8;
    const f16* bp1 = bp0 + (size_t)16 * Ff;
    const f16* bp2 = bp0 + (size_t)32 * Ff;
    const f16* bp3 = bp0 + (size_t)48 * Ff;

    f32x4 av0 = *(const f32x4*)aptr;
    f32x4 av1 = *(const f32x4*)(aptr + 4);
    f16x8 bc0 = *(const f16x8*)bp0;
    f16x8 bc1 = *(const f16x8*)bp1;
    f16x8 bc2 = *(const f16x8*)bp2;
    f16x8 bc3 = *(const f16x8*)bp3;
    f32x4 acc0 = {0.f, 0.f, 0.f, 0.f}, acc1 = acc0, acc2 = acc0, acc3 = acc0;

    for (int k0 = 0; k0 < Ff; k0 += 32) {
        int kn = (k0 + 32 < Ff) ? k0 + 32 : 0;
        f32x4 an0 = *(const f32x4*)(aptr + kn);
        f32x4 an1 = *(const f32x4*)(aptr + kn + 4);
        f16x8 bn0 = *(const f16x8*)(bp0 + kn);
        f16x8 bn1 = *(const f16x8*)(bp1 + kn);
        f16x8 bn2 = *(const f16x8*)(bp2 + kn);
        f16x8 bn3 = *(const f16x8*)(bp3 + kn);
        f16x8 af;
#pragma unroll
        for (int i = 0; i < 4; ++i) { af[i] = (f16)av0[i]; af[4 + i] = (f16)av1[i]; }
        acc0 = __builtin_amdgcn_mfma_f32_16x16x32_f16(af, bc0, acc0, 0, 0, 0);
        acc1 = __builtin_amdgcn_mfma_f32_16x16x32_f16(af, bc1, acc1, 0, 0, 0);
        acc2 = __builtin_amdgcn_mfma_f32_16x16x32_f16(af, bc2, acc2, 0, 0, 0);
        acc3 = __builtin_amdgcn_mfma_f32_16x16x32_f16(af, bc3, acc3, 0, 0, 0);
        av0 = an0; av1 = an1;
        bc0 = bn0; bc1 = bn1; bc2 = bn2; bc3 = bn3;
    }

    // ---- epilogue ----
    int b = m0 >> 11;
    int nn0 = (m0 & 2047) + aq * 4;
    f32x4 accs[4] = {acc0, acc1, acc2, acc3};
#pragma unroll
    for (int t4 = 0; t4 < 4; ++t4) {
        int g = (colb + t4 * 16) >> oshift;
        int o = ((colb + t4 * 16) & (Ofull - 1)) + am;
        size_t bg = (size_t)b * G + g;
        f16x4 ct;
#pragma unroll
        for (int e = 0; e < 4; ++e) ct[e] = (f16)accs[t4][e];
        *(f16x4*)&CT[(bg * Ofull + o) * Nn + nn0] = ct;
    }
#pragma unroll
    for (int gs = 0; gs < 2; ++gs) {
        int g = (colb + gs * 32) >> oshift;
        int o0 = ((colb + gs * 32) & (Ofull - 1)) + am;
        size_t bg = (size_t)b * G + g;
        const float* a1p = pa + 2 * (size_t)g * Ofull;
        float a10 = a1p[o0], a11 = a1p[o0 + 16];
        float a20 = a1p[Ofull + o0], a21 = a1p[Ofull + o0 + 16];
#pragma unroll
        for (int e = 0; e < 4; ++e) {
            float p1 = accs[2 * gs][e] * a10 + accs[2 * gs + 1][e] * a11;
            float p2 = accs[2 * gs][e] * a20 + accs[2 * gs + 1][e] * a21;
#pragma unroll
            for (int s = 1; s < 16; s <<= 1) {
                p1 += __shfl_xor(p1, s);
                p2 += __shfl_xor(p2, s);
            }
            if (am == 0) {
                size_t sidx = bg * Nn + nn0 + e;
                atomicAdd(&s1[sidx], p1);
                atomicAdd(&s2[sidx], p2);
            }
        }
    }
}

// ---------------------------------------------------------------------------
// Barrier-free head attention: wave-private 16 rows x 32 cols.
// e-phase lanes (row=lane>>2, 16 j each) produce exactly this wave's P tile
// in its private LDS slice -> in-wave DS ordering, no __syncthreads ever.
// ---------------------------------------------------------------------------
__global__ __launch_bounds__(256) void attn_head(
    const f16* __restrict__ WhT, const float* __restrict__ s1,
    const float* __restrict__ s2, const u16* __restrict__ maskB,
    float* __restrict__ dst) {
    constexpr int PSTR = 72;
    constexpr float C0 = -ESHIFT * LOG2E - BIGM;
    __shared__ f16 P[4][16 * PSTR];

    int t = threadIdx.x;
    int w = t >> 6, lane = t & 63;
    int i0 = blockIdx.x * 64 + w * 16;
    int bg = blockIdx.z;
    int b = bg >> 3, g = bg & 7;

    int row = lane >> 2, jq = lane & 3;
    int am = lane & 15, aq = lane >> 4;
    f16* Pw = P[w];

    const f16* whT = WhT + (size_t)bg * Oo * Nn;
    const float* s2p = s2 + (size_t)bg * Nn;
    float s1v = s1[(size_t)bg * Nn + i0 + row];
    const u16* mrow = maskB + ((size_t)b * Nn + i0 + row) * (Nn / 16) + jq;

    const f16* bp0 = whT + (size_t)am * Nn + aq * 8;
    const f16* bp1 = whT + (size_t)(16 + am) * Nn + aq * 8;
    f16x8 b00 = *(const f16x8*)bp0;
    f16x8 b01 = *(const f16x8*)(bp0 + 32);
    f16x8 b10 = *(const f16x8*)bp1;
    f16x8 b11 = *(const f16x8*)(bp1 + 32);
    f32x4 acc0 = {0.f, 0.f, 0.f, 0.f}, acc1 = acc0;
    float lacc = 0.f;

    for (int c = 0; c < NC; ++c) {
        int cn = (c + 1 < NC) ? c + 1 : 0;
        f16x8 n00 = *(const f16x8*)(bp0 + cn * 64);
        f16x8 n01 = *(const f16x8*)(bp0 + cn * 64 + 32);
        f16x8 n10 = *(const f16x8*)(bp1 + cn * 64);
        f16x8 n11 = *(const f16x8*)(bp1 + cn * 64 + 32);

        unsigned bits = mrow[c * 4];
        int jb = c * 64 + jq * 16;
        f32x4 sv0 = *(const f32x4*)(s2p + jb);
        f32x4 sv1 = *(const f32x4*)(s2p + jb + 4);
        f32x4 sv2 = *(const f32x4*)(s2p + jb + 8);
        f32x4 sv3 = *(const f32x4*)(s2p + jb + 12);
        f16x8 pv0, pv1;
#pragma unroll
        for (int k = 0; k < 8; ++k) {
            float xv = s1v + (k < 4 ? sv0[k & 3] : sv1[k & 3]);
            float lr = fmaxf(xv, ALPHA_LRELU * xv);
            float bitf = (float)((bits >> k) & 1u);
            float p = EXP2(fmaf(bitf, BIGM, fmaf(lr, LOG2E, C0)));
            lacc += p;
            pv0[k] = (f16)p;
        }
#pragma unroll
        for (int k = 0; k < 8; ++k) {
            float xv = s1v + (k < 4 ? sv2[k & 3] : sv3[k & 3]);
            float lr = fmaxf(xv, ALPHA_LRELU * xv);
            float bitf = (float)((bits >> (8 + k)) & 1u);
            float p = EXP2(fmaf(bitf, BIGM, fmaf(lr, LOG2E, C0)));
            lacc += p;
            pv1[k] = (f16)p;
        }
        *(f16x8*)&Pw[row * PSTR + jq * 16] = pv0;
        *(f16x8*)&Pw[row * PSTR + jq * 16 + 8] = pv1;

        f16x8 a0 = *(const f16x8*)&Pw[am * PSTR + aq * 8];
        f16x8 a1 = *(const f16x8*)&Pw[am * PSTR + 32 + aq * 8];
        acc0 = __builtin_amdgcn_mfma_f32_16x16x32_f16(a0, b00, acc0, 0, 0, 0);
        acc0 = __builtin_amdgcn_mfma_f32_16x16x32_f16(a1, b01, acc0, 0, 0, 0);
        acc1 = __builtin_amdgcn_mfma_f32_16x16x32_f16(a0, b10, acc1, 0, 0, 0);
        acc1 = __builtin_amdgcn_mfma_f32_16x16x32_f16(a1, b11, acc1, 0, 0, 0);
        b00 = n00; b01 = n01; b10 = n10; b11 = n11;
    }

    lacc += __shfl_xor(lacc, 1);
    lacc += __shfl_xor(lacc, 2);
#pragma unroll
    for (int e = 0; e < 4; ++e) {
        int r = aq * 4 + e;
        float li = __shfl(lacc, r * 4);
        float v0 = acc0[e] / li, v1 = acc1[e] / li;
        v0 = v0 > 0.f ? v0 : __expf(v0) - 1.f;
        v1 = v1 > 0.f ? v1 : __expf(v1) - 1.f;
        size_t base = ((size_t)b * Nn + i0 + r) * Ff + g * Oo;
        dst[base + am] = v0;
        dst[base + 16 + am] = v1;
    }
}

// ---------------------------------------------------------------------------
// Barrier-free out attention: wave-private 16 rows x 64 cols (4 col-tiles),
// e-phase recomputed per colgroup (4x) -- cheaper than barriers. Double ELU.
// ---------------------------------------------------------------------------
__global__ __launch_bounds__(256) void attn_out(
    const f16* __restrict__ WhT, const float* __restrict__ s1,
    const float* __restrict__ s2, const u16* __restrict__ maskB,
    float* __restrict__ dst) {
    constexpr int PSTR = 72;
    constexpr float C0 = -ESHIFT * LOG2E - BIGM;
    __shared__ f16 P[4][16 * PSTR];

    int t = threadIdx.x;
    int w = t >> 6, lane = t & 63;
    int i0 = blockIdx.x * 64 + w * 16;
    int colb = blockIdx.y * 64;
    int b = blockIdx.z;

    int row = lane >> 2, jq = lane & 3;
    int am = lane & 15, aq = lane >> 4;
    f16* Pw = P[w];

    const f16* whT = WhT + (size_t)b * Ff * Nn;
    const float* s2p = s2 + (size_t)b * Nn;
    float s1v = s1[(size_t)b * Nn + i0 + row];
    const u16* mrow = maskB + ((size_t)b * Nn + i0 + row) * (Nn / 16) + jq;

    const f16* bp[4];
#pragma unroll
    for (int t4 = 0; t4 < 4; ++t4)
        bp[t4] = whT + (size_t)(colb + t4 * 16 + am) * Nn + aq * 8;
    f16x8 bc[4][2], bn[4][2];
#pragma unroll
    for (int t4 = 0; t4 < 4; ++t4) {
        bc[t4][0] = *(const f16x8*)bp[t4];
        bc[t4][1] = *(const f16x8*)(bp[t4] + 32);
    }
    f32x4 acc[4] = {};
    float lacc = 0.f;

    for (int c = 0; c < NC; ++c) {
        int cn = (c + 1 < NC) ? c + 1 : 0;
#pragma unroll
        for (int t4 = 0; t4 < 4; ++t4) {
            bn[t4][0] = *(const f16x8*)(bp[t4] + cn * 64);
            bn[t4][1] = *(const f16x8*)(bp[t4] + cn * 64 + 32);
        }
        unsigned bits = mrow[c * 4];
        int jb = c * 64 + jq * 16;
        f32x4 sv0 = *(const f32x4*)(s2p + jb);
        f32x4 sv1 = *(const f32x4*)(s2p + jb + 4);
        f32x4 sv2 = *(const f32x4*)(s2p + jb + 8);
        f32x4 sv3 = *(const f32x4*)(s2p + jb + 12);
        f16x8 pv0, pv1;
#pragma unroll
        for (int k = 0; k < 8; ++k) {
            float xv = s1v + (k < 4 ? sv0[k & 3] : sv1[k & 3]);
            float lr = fmaxf(xv, ALPHA_LRELU * xv);
            float bitf = (float)((bits >> k) & 1u);
            float p = EXP2(fmaf(bitf, BIGM, fmaf(lr, LOG2E, C0)));
            lacc += p;
            pv0[k] = (f16)p;
        }
#pragma unroll
        for (int k = 0; k < 8; ++k) {
            float xv = s1v + (k < 4 ? sv2[k & 3] : sv3[k & 3]);
            float lr = fmaxf(xv, ALPHA_LRELU * xv);
            float bitf = (float)((bits >> (8 + k)) & 1u);
            float p = EXP2(fmaf(bitf, BIGM, fmaf(lr, LOG2E, C0)));
            lacc += p;
            pv1[k] = (f16)p;
        }
        *(f16x8*)&Pw[row * PSTR + jq * 16] = pv0;
        *(f16x8*)&Pw[row * PSTR + jq * 16 + 8] = pv1;

        f16x8 a0 = *(const f16x8*)&Pw[am * PSTR + aq * 8];
        f16x8 a1 = *(const f16x8*)&Pw[am * PSTR + 32 + aq * 8];
#pragma unroll
        for (int t4 = 0; t4 < 4; ++t4) {
            acc[t4] = __builtin_amdgcn_mfma_f32_16x16x32_f16(a0, bc[t4][0], acc[t4], 0, 0, 0);
            acc[t4] = __builtin_amdgcn_mfma_f32_16x16x32_f16(a1, bc[t4][1], acc[t4], 0, 0, 0);
            bc[t4][0] = bn[t4][0];
            bc[t4][1] = bn[t4][1];
        }
    }

    lacc += __shfl_xor(lacc, 1);
    lacc += __shfl_xor(lacc, 2);
#pragma unroll
    for (int e = 0; e < 4; ++e) {
        int r = aq * 4 + e;
        float li = __shfl(lacc, r * 4);
        size_t base = ((size_t)b * Nn + i0 + r) * Ff + colb;
#pragma unroll
        for (int t4 = 0; t4 < 4; ++t4) {
            float v = acc[t4][e] / li;
            v = v > 0.f ? v : __expf(v) - 1.f;
            v = v > 0.f ? v : __expf(v) - 1.f;
            dst[base + t4 * 16 + am] = v;
        }
    }
}

// ---------------------------------------------------------------------------
extern "C" void kernel_launch(void* const* d_in, const int* in_sizes, int n_in,
                              void* d_out, int out_size, void* d_ws, size_t ws_size,
                              hipStream_t stream) {
    const float* x = (const float*)d_in[0];
    const int* adj = (const int*)d_in[1];
    const float* W_heads = (const float*)d_in[2];
    const float* a_heads = (const float*)d_in[3];
    const float* W_out = (const float*)d_in[4];
    const float* a_out = (const float*)d_in[5];
    float* out = (float*)d_out;

    float* ws = (float*)d_ws;
    const size_t M = (size_t)Bc * Nn * Ff;  // 1,048,576
    float* h_cur = ws;                      // [B,N,F] fp32
    float* h_tmp = ws + M;                  // [B,N,F] fp32
    f16* WhT = (f16*)(ws + 2 * M);          // [B,G,O,N] f16
    u64* mask = (u64*)(ws + 2 * M + M / 2); // 1 MB
    f16* WT = (f16*)(ws + 2 * M + M / 2 + M / 4);  // 6*F*F f16
    float* sbuf = ws + 2 * M + M / 2 + M / 4 + 196608;
    const size_t SH = (size_t)Bc * Hh * Nn;  // 32768
    const size_t SO = (size_t)Bc * Nn;       // 4096
    const size_t SL = 2 * SH + 2 * SO;

    zero_kernel<<<(3 * SL) / 256, 256, 0, stream>>>(sbuf);
    pack_kernel<<<(Bc * Nn * Nn) / 256, 256, 0, stream>>>(adj, mask);
    wt_kernel<<<dim3(Ff / 4, 6), 256, 0, stream>>>(W_heads, W_out, WT);
    const u16* maskB = (const u16*)mask;

    for (int l = 0; l < 3; ++l) {
        const float* hin = (l == 0) ? x : h_cur;
        float* s1h = sbuf + l * SL;
        float* s2h = s1h + SH;
        float* s1o = s2h + SH;
        float* s2o = s1o + SO;

        // ---- head GAT: G=8, O=32 ----
        gemm_wave<<<dim3((Bc * Nn) / 64, Ff / 64), 256, 0, stream>>>(
            hin, WT + (size_t)(2 * l) * Ff * Ff,
            a_heads + (size_t)l * Hh * 2 * Oo, WhT, s1h, s2h, Hh, Oo, 5);
        attn_head<<<dim3(Nn / 64, 1, Bc * Hh), 256, 0, stream>>>(
            WhT, s1h, s2h, maskB, h_tmp);

        // ---- out GAT: G=1, O=F=256 ----
        gemm_wave<<<dim3((Bc * Nn) / 64, Ff / 64), 256, 0, stream>>>(
            h_tmp, WT + (size_t)(2 * l + 1) * Ff * Ff,
            a_out + (size_t)l * 2 * Ff, WhT, s1o, s2o, 1, Ff, 8);
        float* dstp = (l == 2) ? out : h_cur;
        attn_out<<<dim3(Nn / 64, Ff / 64, Bc), 256, 0, stream>>>(
            WhT, s1o, s2o, maskB, dstp);
    }
}